// Round 18
// baseline (242.957 us; speedup 1.0000x reference)
//
#include <hip/hip_runtime.h>
#include <hip/hip_fp16.h>

static constexpr int NN = 100000;   // nodes
static constexpr int NE = 3200000;  // edges
static constexpr float EPS = 1e-5f;
static constexpr int NB   = 391;    // coarse bins (dst>>8), 256 nodes each
static constexpr int CAP2 = 9216;   // bin capacity (mean 8192 + ~11 sigma)
static constexpr int CH1  = 4096;   // pass-1 edges per block
static constexpr int NBLK1 = (NE + CH1 - 1) / CH1;   // 782

typedef _Float16 h2f __attribute__((ext_vector_type(2)));
typedef float    f4v __attribute__((ext_vector_type(4)));   // nt-store-compatible float4

__device__ __forceinline__ h2f u2h2(unsigned u) {
    union { unsigned u; h2f h; } cv; cv.u = u; return cv.h;
}

// ---- seed per-bin global cursors to padded bin bases ---------------------
__global__ void k_seed(int* __restrict__ gcur) {
    int t = blockIdx.x * blockDim.x + threadIdx.x;
    if (t < NB) gcur[t] = t * CAP2;
}

// ---- pass 1: LDS counting-sort chunk into coarse bins, coalesced out -----
__global__ __launch_bounds__(512) void k_part1(const int* __restrict__ src,
                                               const int* __restrict__ dst,
                                               int* __restrict__ gcur,
                                               unsigned* __restrict__ ebuf) {
    __shared__ unsigned stage[CH1];
    __shared__ unsigned short bins[CH1];
    __shared__ int hist[NB], lbase[NB + 1], lcur[NB], gbase[NB];
    int tid = threadIdx.x;
    int e0 = blockIdx.x * CH1;
    int n = min(CH1, NE - e0);

    for (int t = tid; t < NB; t += 512) { hist[t] = 0; lcur[t] = 0; }
    __syncthreads();
    for (int i = tid; i < n; i += 512) atomicAdd(&hist[dst[e0 + i] >> 8], 1);
    __syncthreads();
    for (int t = tid; t < NB; t += 512) gbase[t] = atomicAdd(&gcur[t], hist[t]);
    if (tid < 64) {                       // wave exclusive scan hist -> lbase
        int lane = tid, sum = 0, pre[7];
        #pragma unroll
        for (int k = 0; k < 7; ++k) {
            int idx = lane * 7 + k;
            int v = (idx < NB) ? hist[idx] : 0;
            pre[k] = sum; sum += v;
        }
        int inc = sum;
        #pragma unroll
        for (int off = 1; off < 64; off <<= 1) {
            int t = __shfl_up(inc, off);
            if (lane >= off) inc += t;
        }
        int excl = inc - sum;
        #pragma unroll
        for (int k = 0; k < 7; ++k) {
            int idx = lane * 7 + k;
            if (idx < NB + 1) lbase[idx] = excl + pre[k];
        }
    }
    __syncthreads();
    for (int i = tid; i < n; i += 512) {
        int d = dst[e0 + i];
        int b = d >> 8;
        int r = atomicAdd(&lcur[b], 1);
        int p = lbase[b] + r;
        stage[p] = ((unsigned)(d & 255) << 17) | (unsigned)src[e0 + i];
        bins[p] = (unsigned short)b;
    }
    __syncthreads();
    for (int i = tid; i < n; i += 512) {
        int b = bins[i];
        ebuf[gbase[b] + (i - lbase[b])] = stage[i];
    }
}

// ---- exact bin-base scan (392 values) ------------------------------------
__global__ void k_binscan(const int* __restrict__ gcur, int* __restrict__ binBase) {
    __shared__ int s[512];
    int t = threadIdx.x;
    int v = (t < NB) ? (gcur[t] - t * CAP2) : 0;
    s[t] = v;
    __syncthreads();
    for (int off = 1; off < 512; off <<= 1) {
        int x = (t >= off) ? s[t - off] : 0;
        __syncthreads();
        s[t] += x;
        __syncthreads();
    }
    if (t < NB + 1) binBase[t] = s[t] - v;   // exclusive (v=0 for t==NB)
}

// ---- pass 2: fine sort bin -> CSR + rowp/cnt/dinv + fused f16 stage1 ------
__global__ __launch_bounds__(512) void k_part2(const unsigned* __restrict__ ebuf,
                                               const int* __restrict__ binBase,
                                               int* __restrict__ csr, int* __restrict__ rowp,
                                               int* __restrict__ cnt, float* __restrict__ dinv,
                                               const float* __restrict__ x,
                                               __half* __restrict__ q) {
    __shared__ unsigned s2[CAP2];
    __shared__ int lhist[256], lrow[257];
    __shared__ float ldinv[256];
    int tid = threadIdx.x, b = blockIdx.x;
    int base = b * CAP2;
    int o0 = binBase[b], m = binBase[b + 1] - o0;

    if (tid < 256) lhist[tid] = 0;
    __syncthreads();
    for (int i = tid; i < m; i += 512) atomicAdd(&lhist[ebuf[base + i] >> 17], 1);
    __syncthreads();
    if (tid < 64) {                       // wave exclusive scan lhist -> lrow
        int lane = tid, sum = 0, pre[4];
        #pragma unroll
        for (int k = 0; k < 4; ++k) { pre[k] = sum; sum += lhist[lane * 4 + k]; }
        int inc = sum;
        #pragma unroll
        for (int off = 1; off < 64; off <<= 1) {
            int t = __shfl_up(inc, off);
            if (lane >= off) inc += t;
        }
        int excl = inc - sum;
        #pragma unroll
        for (int k = 0; k < 4; ++k) lrow[lane * 4 + k] = excl + pre[k];
        if (lane == 63) lrow[256] = excl + sum;
    }
    __syncthreads();
    if (tid < 256) lhist[tid] = 0;        // reuse as cursor
    __syncthreads();
    for (int i = tid; i < m; i += 512) {
        unsigned p = ebuf[base + i];
        int nd = (int)(p >> 17);
        int r = atomicAdd(&lhist[nd], 1);
        s2[lrow[nd] + r] = p & 0x1FFFFu;
    }
    __syncthreads();
    for (int i = tid; i < m; i += 512) csr[o0 + i] = (int)s2[i];
    int ng = (b << 8) + tid;
    if (tid < 256 && ng < NN) {
        int c = lrow[tid + 1] - lrow[tid];
        rowp[ng] = o0 + lrow[tid];
        cnt[ng] = c;
        float dv = rsqrtf((float)c + 1.f);
        dinv[ng] = dv;
        ldinv[tid] = dv;
    }
    __syncthreads();
    // fused layer-1 staging (f16): q[node, 0..7] = dinv*x[node, 0..4], pad 0
    int nmax = min(256, NN - (b << 8));
    for (int idx = tid; idx < nmax * 8; idx += 512) {
        int nl = idx >> 3, k = idx & 7;
        int node = (b << 8) + nl;
        q[(size_t)node * 8 + k] = __float2half((k < 5) ? x[node * 5 + k] * ldinv[nl] : 0.f);
    }
}

// ---- LDS-tiled dense linear ----------------------------------------------
// MODE 0: out f32 = a*dinv, OUTP-padded rows.   (layer 4 pre-gather)
// MODE 1: out f16 = a*dinv.                      (layers 2,3 pre-gather)
// MODE 2: out f32 = relu(bn(a + b)).             (layer-1 tail)
template<int INP, int IN, int OUT, int OUTP, int MODE>
__global__ __launch_bounds__(256) void k_lin(
        const float* __restrict__ in, const float* __restrict__ W,
        const float* __restrict__ dinv, const float* __restrict__ b,
        const float* __restrict__ g, const float* __restrict__ be,
        const float* __restrict__ m, const float* __restrict__ vv,
        float* __restrict__ outf, __half* __restrict__ outh) {
    constexpr int NPB = 256 / OUTP;   // nodes per block
    __shared__ float srow[NPB * INP];
    __shared__ float sW[IN * OUT];
    int tid = threadIdx.x;
    size_t node0 = (size_t)blockIdx.x * NPB;

    for (int t = tid; t < IN * OUT; t += 256) sW[t] = W[t];
    const float4* in4 = reinterpret_cast<const float4*>(in + node0 * INP);
    float4* s4 = reinterpret_cast<float4*>(srow);
    constexpr int TOT4 = NPB * INP / 4;
    #pragma unroll 1
    for (int t = tid; t < TOT4; t += 256) s4[t] = in4[t];
    __syncthreads();

    int il = tid / OUTP, f = tid - il * OUTP;
    size_t node = node0 + il;
    if (node >= NN) return;
    const float* row = srow + il * INP;
    float a = 0.f;
    if (f < OUT) {
        #pragma unroll
        for (int k = 0; k < IN; ++k) a += row[k] * sW[k * OUT + f];
    }
    if constexpr (MODE == 0) {
        outf[node * OUTP + f] = (f < OUT) ? a * dinv[node] : 0.f;
    } else if constexpr (MODE == 1) {
        outh[node * OUT + f] = __float2half(a * dinv[node]);
    } else {
        float z = a + b[f];
        z = (z - m[f]) * rsqrtf(vv[f] + EPS) * g[f] + be[f];
        outf[node * OUT + f] = fmaxf(z, 0.f);
    }
}

// ---- f32 gather: FOUR nodes per wave (16-lane groups), layer 4 ------------
// MODE 3: bias + write 3 floats (logits).
template<int F, int MODE>
__global__ __launch_bounds__(256) void k_gather(
        const int* __restrict__ row_ptr, const int* __restrict__ cnt,
        const int* __restrict__ csr, const float* __restrict__ hs,
        const float* __restrict__ dinv, const float* __restrict__ b,
        float* __restrict__ out) {
    constexpr int F4   = F / 4;       // lanes per edge (float4 each)
    constexpr int EPI  = 16 / F4;     // edges per iteration per group
    constexpr int ITER = F4;

    int wid  = (blockIdx.x * blockDim.x + threadIdx.x) >> 6;
    int lane = threadIdx.x & 63;
    int grp  = lane >> 4, hl = lane & 15;
    int node = wid * 4 + grp;
    if (node >= NN) return;
    int c = hl & (F4 - 1);
    int e = hl / F4;

    int start = row_ptr[node];
    int n     = cnt[node];

    float4 a = make_float4(0.f, 0.f, 0.f, 0.f);
    for (int base = 0; base < n; base += 16) {
        int rem = n - base;
        int my = (hl < rem) ? __builtin_nontemporal_load(&csr[start + base + hl]) : 0;
        #pragma unroll
        for (int k = 0; k < ITER; ++k) {
            if (k * EPI >= rem) break;        // per-group, exec-masked
            int j = e + k * EPI;
            int t = __shfl(my, grp * 16 + j);
            bool act = (j < rem);
            int s = act ? t : 0;
            float4 v = reinterpret_cast<const float4*>(hs + (size_t)s * F)[c];
            if (act) { a.x += v.x; a.y += v.y; a.z += v.z; a.w += v.w; }
        }
    }
    #pragma unroll
    for (int mask = F4; mask < 16; mask <<= 1) {
        a.x += __shfl_xor(a.x, mask);
        a.y += __shfl_xor(a.y, mask);
        a.z += __shfl_xor(a.z, mask);
        a.w += __shfl_xor(a.w, mask);
    }

    if (hl < F4) {
        float4 self = reinterpret_cast<const float4*>(hs + (size_t)node * F)[hl];
        float di = dinv[node];
        float4 z;
        z.x = di * (a.x + self.x);
        z.y = di * (a.y + self.y);
        z.z = di * (a.z + self.z);
        z.w = di * (a.w + self.w);
        if constexpr (MODE == 3) {
            float* o = out + (size_t)node * 3;
            __builtin_nontemporal_store(z.x + b[0], o + 0);
            __builtin_nontemporal_store(z.y + b[1], o + 1);
            __builtin_nontemporal_store(z.z + b[2], o + 2);
        } else {
            f4v zz = {z.x, z.y, z.z, z.w};
            __builtin_nontemporal_store(zz, reinterpret_cast<f4v*>(out + (size_t)node * F) + hl);
        }
    }
}

// ---- f16 gather: FOUR nodes per wave, 16B/lane (8 halves), fdot2 ----------
// MODE 0: scale only.  MODE 1: bias+relu.  MODE 2: bias+bn+relu.
template<int F, int MODE, int OSTRIDE>
__global__ __launch_bounds__(256) void k_gather_h(
        const int* __restrict__ row_ptr, const int* __restrict__ cnt,
        const int* __restrict__ csr, const __half* __restrict__ hs,
        const float* __restrict__ dinv, const float* __restrict__ b,
        const float* __restrict__ g, const float* __restrict__ be,
        const float* __restrict__ m, const float* __restrict__ vv,
        float* __restrict__ out) {
    constexpr int F4   = F / 8;       // lanes per edge (8 halves = 16B each)
    constexpr int EPI  = 16 / F4;     // edges per iteration per group
    constexpr int ITER = F4;          // EPI*ITER = 16

    int wid  = (blockIdx.x * blockDim.x + threadIdx.x) >> 6;
    int lane = threadIdx.x & 63;
    int grp  = lane >> 4, hl = lane & 15;
    int node = wid * 4 + grp;
    if (node >= NN) return;
    int c = hl & (F4 - 1);
    int e = hl / F4;

    int start = row_ptr[node];
    int n     = cnt[node];

    const h2f SEL_A = {(_Float16)1.f, (_Float16)0.f};
    const h2f SEL_B = {(_Float16)0.f, (_Float16)1.f};
    const h2f SEL_Z = {(_Float16)0.f, (_Float16)0.f};

    float4 a0 = make_float4(0.f, 0.f, 0.f, 0.f);
    float4 a1 = make_float4(0.f, 0.f, 0.f, 0.f);
    for (int base = 0; base < n; base += 16) {
        int rem = n - base;
        int my = (hl < rem) ? __builtin_nontemporal_load(&csr[start + base + hl]) : 0;
        #pragma unroll
        for (int k = 0; k < ITER; ++k) {
            if (k * EPI >= rem) break;        // per-group, exec-masked
            int j = e + k * EPI;
            int t = __shfl(my, grp * 16 + j);
            bool act = (j < rem);
            int s = act ? t : 0;
            uint4 r = reinterpret_cast<const uint4*>(hs + (size_t)s * F)[c];
            h2f sA = act ? SEL_A : SEL_Z;
            h2f sB = act ? SEL_B : SEL_Z;
            h2f h0 = u2h2(r.x), h1 = u2h2(r.y), h2 = u2h2(r.z), h3 = u2h2(r.w);
            a0.x = __builtin_amdgcn_fdot2(h0, sA, a0.x, false);
            a0.y = __builtin_amdgcn_fdot2(h0, sB, a0.y, false);
            a0.z = __builtin_amdgcn_fdot2(h1, sA, a0.z, false);
            a0.w = __builtin_amdgcn_fdot2(h1, sB, a0.w, false);
            a1.x = __builtin_amdgcn_fdot2(h2, sA, a1.x, false);
            a1.y = __builtin_amdgcn_fdot2(h2, sB, a1.y, false);
            a1.z = __builtin_amdgcn_fdot2(h3, sA, a1.z, false);
            a1.w = __builtin_amdgcn_fdot2(h3, sB, a1.w, false);
        }
    }
    #pragma unroll
    for (int mask = F4; mask < 16; mask <<= 1) {
        a0.x += __shfl_xor(a0.x, mask);
        a0.y += __shfl_xor(a0.y, mask);
        a0.z += __shfl_xor(a0.z, mask);
        a0.w += __shfl_xor(a0.w, mask);
        a1.x += __shfl_xor(a1.x, mask);
        a1.y += __shfl_xor(a1.y, mask);
        a1.z += __shfl_xor(a1.z, mask);
        a1.w += __shfl_xor(a1.w, mask);
    }

    if (hl < F4) {
        uint4 r = reinterpret_cast<const uint4*>(hs + (size_t)node * F)[hl];
        float2 s0 = __half22float2(*reinterpret_cast<__half2*>(&r.x));
        float2 s1 = __half22float2(*reinterpret_cast<__half2*>(&r.y));
        float2 s2 = __half22float2(*reinterpret_cast<__half2*>(&r.z));
        float2 s3 = __half22float2(*reinterpret_cast<__half2*>(&r.w));
        float di = dinv[node];
        int f0 = hl * 8;
        float z[8];
        z[0] = di * (a0.x + s0.x); z[1] = di * (a0.y + s0.y);
        z[2] = di * (a0.z + s1.x); z[3] = di * (a0.w + s1.y);
        z[4] = di * (a1.x + s2.x); z[5] = di * (a1.y + s2.y);
        z[6] = di * (a1.z + s3.x); z[7] = di * (a1.w + s3.y);
        if constexpr (MODE >= 1) {
            #pragma unroll
            for (int q = 0; q < 8; ++q) {
                float zz = z[q] + b[f0 + q];
                if constexpr (MODE == 2)
                    zz = (zz - m[f0+q]) * rsqrtf(vv[f0+q] + EPS) * g[f0+q] + be[f0+q];
                z[q] = fmaxf(zz, 0.f);
            }
        }
        f4v* o = reinterpret_cast<f4v*>(out + (size_t)node * OSTRIDE + f0);
        f4v z0 = {z[0], z[1], z[2], z[3]};
        f4v z1 = {z[4], z[5], z[6], z[7]};
        __builtin_nontemporal_store(z0, o);
        __builtin_nontemporal_store(z1, o + 1);
    }
}

extern "C" void kernel_launch(void* const* d_in, const int* in_sizes, int n_in,
                              void* d_out, int out_size, void* d_ws, size_t ws_size,
                              hipStream_t stream) {
    const float* x   = (const float*)d_in[0];
    const int*   src = (const int*)  d_in[1];
    const int*   dst = (const int*)  d_in[2];
    const float* W1  = (const float*)d_in[3];
    const float* b1  = (const float*)d_in[4];
    const float* g1  = (const float*)d_in[5];
    const float* be1 = (const float*)d_in[6];
    const float* m1  = (const float*)d_in[7];
    const float* v1  = (const float*)d_in[8];
    const float* W2  = (const float*)d_in[9];
    const float* b2  = (const float*)d_in[10];
    const float* g2  = (const float*)d_in[11];
    const float* be2 = (const float*)d_in[12];
    const float* m2  = (const float*)d_in[13];
    const float* v2  = (const float*)d_in[14];
    const float* W3  = (const float*)d_in[15];
    const float* b3  = (const float*)d_in[16];
    const float* W4  = (const float*)d_in[17];
    const float* b4  = (const float*)d_in[18];
    float* out = (float*)d_out;

    // workspace layout (4-byte units)
    char* wsb = (char*)d_ws;
    float*    dinv    = (float*)wsb;                    // 100352
    int*      cnt     = (int*)(wsb + 100352ull * 4);    // 100352
    int*      rowp    = (int*)(wsb + 200704ull * 4);    // 100352
    int*      gcur    = (int*)(wsb + 301056ull * 4);    // 512
    int*      binBase = (int*)(wsb + 301568ull * 4);    // 512
    int*      csr     = (int*)(wsb + 302080ull * 4);    // NE
    float*    HS      = (float*)(wsb + (302080ull + NE) * 4);              // NN*64 region
    __half*   HSh     = (__half*)HS;                                        // f16 view
    float*    X       = (float*)(wsb + (302080ull + NE + 6400000ull) * 4); // NN*64
    unsigned* ebuf    = (unsigned*)X;  // aliases X (NB*CAP2 = 3.6M <= 6.4M)
    float*    G       = (float*)(wsb + (302080ull + NE + 12800000ull) * 4); // NN*8

    const int BLK = 256;
    const int gW4 = ((NN + 3) / 4 * 64 + BLK - 1) / BLK;   // four nodes per wave

    // ---- CSR build (2-pass LDS counting sort) + rowp/cnt/dinv + f16 stage1 ----
    k_seed   <<<2, 256, 0, stream>>>(gcur);
    k_part1  <<<NBLK1, 512, 0, stream>>>(src, dst, gcur, ebuf);
    k_binscan<<<1, 512, 0, stream>>>(gcur, binBase);
    k_part2  <<<NB, 512, 0, stream>>>(ebuf, binBase, csr, rowp, cnt, dinv, x, HSh);

    // ---- Layer 1: f16 gather at F_in=5 (pad 8), then 5->64 GEMM+BN+ReLU ----
    k_gather_h<8, 0, 8><<<gW4, BLK, 0, stream>>>(rowp, cnt, csr, HSh, dinv,
        nullptr, nullptr, nullptr, nullptr, nullptr, G);
    k_lin<8, 5, 64, 64, 2><<<(NN + 3) / 4, BLK, 0, stream>>>(
        G, W1, nullptr, b1, g1, be1, m1, v1, X, nullptr);

    // ---- Layer 2: 64 -> 32 GEMM (f16 table), single 32-wide gather ----
    k_lin<64, 64, 32, 32, 1><<<(NN + 7) / 8, BLK, 0, stream>>>(
        X, W2, dinv, nullptr, nullptr, nullptr, nullptr, nullptr, nullptr, HSh);
    k_gather_h<32, 2, 32><<<gW4, BLK, 0, stream>>>(rowp, cnt, csr, HSh, dinv,
        b2, g2, be2, m2, v2, X);

    // ---- Layer 3: 32 -> 16 GEMM (f16 table), gather, ReLU ----
    k_lin<32, 32, 16, 16, 1><<<(NN + 15) / 16, BLK, 0, stream>>>(
        X, W3, dinv, nullptr, nullptr, nullptr, nullptr, nullptr, nullptr, HSh);
    k_gather_h<16, 1, 16><<<gW4, BLK, 0, stream>>>(rowp, cnt, csr, HSh, dinv,
        b3, nullptr, nullptr, nullptr, nullptr, X);

    // ---- Layer 4: 16 -> 3 GEMM (pad 4, f32), gather, logits ----
    k_lin<16, 16, 3, 4, 0><<<(NN + 63) / 64, BLK, 0, stream>>>(
        X, W4, dinv, nullptr, nullptr, nullptr, nullptr, nullptr, HS, nullptr);
    k_gather<4, 3><<<gW4, BLK, 0, stream>>>(rowp, cnt, csr, HS, dinv, b4, out);
}

// Round 19
// 219.794 us; speedup vs baseline: 1.1054x; 1.1054x over previous
//
#include <hip/hip_runtime.h>
#include <hip/hip_fp16.h>

static constexpr int NN = 100000;   // nodes
static constexpr int NE = 3200000;  // edges
static constexpr float EPS = 1e-5f;
static constexpr int NB   = 391;    // coarse bins (dst>>8), 256 nodes each
static constexpr int CAP2 = 9216;   // bin capacity (mean 8192 + ~11 sigma)
static constexpr int CH1  = 4096;   // pass-1 edges per block
static constexpr int NBLK1 = (NE + CH1 - 1) / CH1;   // 782

typedef _Float16 h2f __attribute__((ext_vector_type(2)));

__device__ __forceinline__ h2f u2h2(unsigned u) {
    union { unsigned u; h2f h; } cv; cv.u = u; return cv.h;
}

// ---- seed per-bin global cursors to padded bin bases ---------------------
__global__ void k_seed(int* __restrict__ gcur) {
    int t = blockIdx.x * blockDim.x + threadIdx.x;
    if (t < NB) gcur[t] = t * CAP2;
}

// ---- pass 1: LDS counting-sort chunk into coarse bins, coalesced out -----
__global__ __launch_bounds__(512) void k_part1(const int* __restrict__ src,
                                               const int* __restrict__ dst,
                                               int* __restrict__ gcur,
                                               unsigned* __restrict__ ebuf) {
    __shared__ unsigned stage[CH1];
    __shared__ unsigned short bins[CH1];
    __shared__ int hist[NB], lbase[NB + 1], lcur[NB], gbase[NB];
    int tid = threadIdx.x;
    int e0 = blockIdx.x * CH1;
    int n = min(CH1, NE - e0);

    for (int t = tid; t < NB; t += 512) { hist[t] = 0; lcur[t] = 0; }
    __syncthreads();
    for (int i = tid; i < n; i += 512) atomicAdd(&hist[dst[e0 + i] >> 8], 1);
    __syncthreads();
    for (int t = tid; t < NB; t += 512) gbase[t] = atomicAdd(&gcur[t], hist[t]);
    if (tid < 64) {                       // wave exclusive scan hist -> lbase
        int lane = tid, sum = 0, pre[7];
        #pragma unroll
        for (int k = 0; k < 7; ++k) {
            int idx = lane * 7 + k;
            int v = (idx < NB) ? hist[idx] : 0;
            pre[k] = sum; sum += v;
        }
        int inc = sum;
        #pragma unroll
        for (int off = 1; off < 64; off <<= 1) {
            int t = __shfl_up(inc, off);
            if (lane >= off) inc += t;
        }
        int excl = inc - sum;
        #pragma unroll
        for (int k = 0; k < 7; ++k) {
            int idx = lane * 7 + k;
            if (idx < NB + 1) lbase[idx] = excl + pre[k];
        }
    }
    __syncthreads();
    for (int i = tid; i < n; i += 512) {
        int d = dst[e0 + i];
        int b = d >> 8;
        int r = atomicAdd(&lcur[b], 1);
        int p = lbase[b] + r;
        stage[p] = ((unsigned)(d & 255) << 17) | (unsigned)src[e0 + i];
        bins[p] = (unsigned short)b;
    }
    __syncthreads();
    for (int i = tid; i < n; i += 512) {
        int b = bins[i];
        ebuf[gbase[b] + (i - lbase[b])] = stage[i];
    }
}

// ---- exact bin-base scan (392 values) ------------------------------------
__global__ void k_binscan(const int* __restrict__ gcur, int* __restrict__ binBase) {
    __shared__ int s[512];
    int t = threadIdx.x;
    int v = (t < NB) ? (gcur[t] - t * CAP2) : 0;
    s[t] = v;
    __syncthreads();
    for (int off = 1; off < 512; off <<= 1) {
        int x = (t >= off) ? s[t - off] : 0;
        __syncthreads();
        s[t] += x;
        __syncthreads();
    }
    if (t < NB + 1) binBase[t] = s[t] - v;   // exclusive (v=0 for t==NB)
}

// ---- pass 2: fine sort bin -> CSR + rowp/cnt/dinv + fused f16 stage1 ------
__global__ __launch_bounds__(512) void k_part2(const unsigned* __restrict__ ebuf,
                                               const int* __restrict__ binBase,
                                               int* __restrict__ csr, int* __restrict__ rowp,
                                               int* __restrict__ cnt, float* __restrict__ dinv,
                                               const float* __restrict__ x,
                                               __half* __restrict__ q) {
    __shared__ unsigned s2[CAP2];
    __shared__ int lhist[256], lrow[257];
    __shared__ float ldinv[256];
    int tid = threadIdx.x, b = blockIdx.x;
    int base = b * CAP2;
    int o0 = binBase[b], m = binBase[b + 1] - o0;

    if (tid < 256) lhist[tid] = 0;
    __syncthreads();
    for (int i = tid; i < m; i += 512) atomicAdd(&lhist[ebuf[base + i] >> 17], 1);
    __syncthreads();
    if (tid < 64) {                       // wave exclusive scan lhist -> lrow
        int lane = tid, sum = 0, pre[4];
        #pragma unroll
        for (int k = 0; k < 4; ++k) { pre[k] = sum; sum += lhist[lane * 4 + k]; }
        int inc = sum;
        #pragma unroll
        for (int off = 1; off < 64; off <<= 1) {
            int t = __shfl_up(inc, off);
            if (lane >= off) inc += t;
        }
        int excl = inc - sum;
        #pragma unroll
        for (int k = 0; k < 4; ++k) lrow[lane * 4 + k] = excl + pre[k];
        if (lane == 63) lrow[256] = excl + sum;
    }
    __syncthreads();
    if (tid < 256) lhist[tid] = 0;        // reuse as cursor
    __syncthreads();
    for (int i = tid; i < m; i += 512) {
        unsigned p = ebuf[base + i];
        int nd = (int)(p >> 17);
        int r = atomicAdd(&lhist[nd], 1);
        s2[lrow[nd] + r] = p & 0x1FFFFu;
    }
    __syncthreads();
    for (int i = tid; i < m; i += 512) csr[o0 + i] = (int)s2[i];
    int ng = (b << 8) + tid;
    if (tid < 256 && ng < NN) {
        int c = lrow[tid + 1] - lrow[tid];
        rowp[ng] = o0 + lrow[tid];
        cnt[ng] = c;
        float dv = rsqrtf((float)c + 1.f);
        dinv[ng] = dv;
        ldinv[tid] = dv;
    }
    __syncthreads();
    // fused layer-1 staging (f16): q[node, 0..7] = dinv*x[node, 0..4], pad 0
    int nmax = min(256, NN - (b << 8));
    for (int idx = tid; idx < nmax * 8; idx += 512) {
        int nl = idx >> 3, k = idx & 7;
        int node = (b << 8) + nl;
        q[(size_t)node * 8 + k] = __float2half((k < 5) ? x[node * 5 + k] * ldinv[nl] : 0.f);
    }
}

// ---- LDS-tiled dense linear ----------------------------------------------
// MODE 1: out f16 = a*dinv.                      (layer 2,3 pre-gather)
// MODE 2: out f32 = relu(bn(a + b)).             (layer-1 tail)
template<int INP, int IN, int OUT, int OUTP, int MODE>
__global__ __launch_bounds__(256) void k_lin(
        const float* __restrict__ in, const float* __restrict__ W,
        const float* __restrict__ dinv, const float* __restrict__ b,
        const float* __restrict__ g, const float* __restrict__ be,
        const float* __restrict__ m, const float* __restrict__ vv,
        float* __restrict__ outf, __half* __restrict__ outh) {
    constexpr int NPB = 256 / OUTP;   // nodes per block
    __shared__ float srow[NPB * INP];
    __shared__ float sW[IN * OUT];
    int tid = threadIdx.x;
    size_t node0 = (size_t)blockIdx.x * NPB;

    for (int t = tid; t < IN * OUT; t += 256) sW[t] = W[t];
    const float4* in4 = reinterpret_cast<const float4*>(in + node0 * INP);
    float4* s4 = reinterpret_cast<float4*>(srow);
    constexpr int TOT4 = NPB * INP / 4;
    #pragma unroll 1
    for (int t = tid; t < TOT4; t += 256) s4[t] = in4[t];
    __syncthreads();

    int il = tid / OUTP, f = tid - il * OUTP;
    size_t node = node0 + il;
    if (node >= NN) return;
    const float* row = srow + il * INP;
    float a = 0.f;
    if (f < OUT) {
        #pragma unroll
        for (int k = 0; k < IN; ++k) a += row[k] * sW[k * OUT + f];
    }
    if constexpr (MODE == 1) {
        outh[node * OUT + f] = __float2half(a * dinv[node]);
    } else {
        float z = a + b[f];
        z = (z - m[f]) * rsqrtf(vv[f] + EPS) * g[f] + be[f];
        outf[node * OUT + f] = fmaxf(z, 0.f);
    }
}

// ---- f32 gather: FOUR nodes per wave (16-lane groups), layer 4 ------------
// MODE 3: bias + write 3 floats (logits).
template<int F, int MODE>
__global__ __launch_bounds__(256) void k_gather(
        const int* __restrict__ row_ptr, const int* __restrict__ cnt,
        const int* __restrict__ csr, const float* __restrict__ hs,
        const float* __restrict__ dinv, const float* __restrict__ b,
        float* __restrict__ out) {
    constexpr int F4   = F / 4;       // lanes per edge (float4 each)
    constexpr int EPI  = 16 / F4;     // edges per iteration per group
    constexpr int ITER = F4;

    int wid  = (blockIdx.x * blockDim.x + threadIdx.x) >> 6;
    int lane = threadIdx.x & 63;
    int grp  = lane >> 4, hl = lane & 15;
    int node = wid * 4 + grp;
    if (node >= NN) return;
    int c = hl & (F4 - 1);
    int e = hl / F4;

    int start = row_ptr[node];
    int n     = cnt[node];

    float4 a = make_float4(0.f, 0.f, 0.f, 0.f);
    for (int base = 0; base < n; base += 16) {
        int rem = n - base;
        int my = (hl < rem) ? csr[start + base + hl] : 0;
        #pragma unroll
        for (int k = 0; k < ITER; ++k) {
            if (k * EPI >= rem) break;        // per-group, exec-masked
            int j = e + k * EPI;
            int t = __shfl(my, grp * 16 + j);
            bool act = (j < rem);
            int s = act ? t : 0;
            float4 v = reinterpret_cast<const float4*>(hs + (size_t)s * F)[c];
            if (act) { a.x += v.x; a.y += v.y; a.z += v.z; a.w += v.w; }
        }
    }
    #pragma unroll
    for (int mask = F4; mask < 16; mask <<= 1) {
        a.x += __shfl_xor(a.x, mask);
        a.y += __shfl_xor(a.y, mask);
        a.z += __shfl_xor(a.z, mask);
        a.w += __shfl_xor(a.w, mask);
    }

    if (hl < F4) {
        float4 self = reinterpret_cast<const float4*>(hs + (size_t)node * F)[hl];
        float di = dinv[node];
        float4 z;
        z.x = di * (a.x + self.x);
        z.y = di * (a.y + self.y);
        z.z = di * (a.z + self.z);
        z.w = di * (a.w + self.w);
        if constexpr (MODE == 3) {
            float* o = out + (size_t)node * 3;
            o[0] = z.x + b[0]; o[1] = z.y + b[1]; o[2] = z.z + b[2];
        } else {
            reinterpret_cast<float4*>(out + (size_t)node * F)[hl] = z;
        }
    }
}

// ---- f16 gather: FOUR nodes per wave, 16B/lane (8 halves), fdot2 ----------
// MODE 0: scale only.  MODE 1: bias+relu.  MODE 2: bias+bn+relu.
// MODE 4: bias+relu then fused 16->3 linear (Wf via g) -> padded-4 f32 out.
template<int F, int MODE, int OSTRIDE>
__global__ __launch_bounds__(256) void k_gather_h(
        const int* __restrict__ row_ptr, const int* __restrict__ cnt,
        const int* __restrict__ csr, const __half* __restrict__ hs,
        const float* __restrict__ dinv, const float* __restrict__ b,
        const float* __restrict__ g, const float* __restrict__ be,
        const float* __restrict__ m, const float* __restrict__ vv,
        float* __restrict__ out) {
    constexpr int F4   = F / 8;       // lanes per edge (8 halves = 16B each)
    constexpr int EPI  = 16 / F4;     // edges per iteration per group
    constexpr int ITER = F4;          // EPI*ITER = 16

    int wid  = (blockIdx.x * blockDim.x + threadIdx.x) >> 6;
    int lane = threadIdx.x & 63;
    int grp  = lane >> 4, hl = lane & 15;
    int node = wid * 4 + grp;
    if (node >= NN) return;
    int c = hl & (F4 - 1);
    int e = hl / F4;

    int start = row_ptr[node];
    int n     = cnt[node];

    const h2f SEL_A = {(_Float16)1.f, (_Float16)0.f};
    const h2f SEL_B = {(_Float16)0.f, (_Float16)1.f};
    const h2f SEL_Z = {(_Float16)0.f, (_Float16)0.f};

    float4 a0 = make_float4(0.f, 0.f, 0.f, 0.f);
    float4 a1 = make_float4(0.f, 0.f, 0.f, 0.f);
    for (int base = 0; base < n; base += 16) {
        int rem = n - base;
        int my = (hl < rem) ? csr[start + base + hl] : 0;
        #pragma unroll
        for (int k = 0; k < ITER; ++k) {
            if (k * EPI >= rem) break;        // per-group, exec-masked
            int j = e + k * EPI;
            int t = __shfl(my, grp * 16 + j);
            bool act = (j < rem);
            int s = act ? t : 0;
            uint4 r = reinterpret_cast<const uint4*>(hs + (size_t)s * F)[c];
            h2f sA = act ? SEL_A : SEL_Z;
            h2f sB = act ? SEL_B : SEL_Z;
            h2f h0 = u2h2(r.x), h1 = u2h2(r.y), h2 = u2h2(r.z), h3 = u2h2(r.w);
            a0.x = __builtin_amdgcn_fdot2(h0, sA, a0.x, false);
            a0.y = __builtin_amdgcn_fdot2(h0, sB, a0.y, false);
            a0.z = __builtin_amdgcn_fdot2(h1, sA, a0.z, false);
            a0.w = __builtin_amdgcn_fdot2(h1, sB, a0.w, false);
            a1.x = __builtin_amdgcn_fdot2(h2, sA, a1.x, false);
            a1.y = __builtin_amdgcn_fdot2(h2, sB, a1.y, false);
            a1.z = __builtin_amdgcn_fdot2(h3, sA, a1.z, false);
            a1.w = __builtin_amdgcn_fdot2(h3, sB, a1.w, false);
        }
    }
    #pragma unroll
    for (int mask = F4; mask < 16; mask <<= 1) {
        a0.x += __shfl_xor(a0.x, mask);
        a0.y += __shfl_xor(a0.y, mask);
        a0.z += __shfl_xor(a0.z, mask);
        a0.w += __shfl_xor(a0.w, mask);
        a1.x += __shfl_xor(a1.x, mask);
        a1.y += __shfl_xor(a1.y, mask);
        a1.z += __shfl_xor(a1.z, mask);
        a1.w += __shfl_xor(a1.w, mask);
    }

    if (hl < F4) {
        uint4 r = reinterpret_cast<const uint4*>(hs + (size_t)node * F)[hl];
        float2 s0 = __half22float2(*reinterpret_cast<__half2*>(&r.x));
        float2 s1 = __half22float2(*reinterpret_cast<__half2*>(&r.y));
        float2 s2 = __half22float2(*reinterpret_cast<__half2*>(&r.z));
        float2 s3 = __half22float2(*reinterpret_cast<__half2*>(&r.w));
        float di = dinv[node];
        int f0 = hl * 8;
        float z[8];
        z[0] = di * (a0.x + s0.x); z[1] = di * (a0.y + s0.y);
        z[2] = di * (a0.z + s1.x); z[3] = di * (a0.w + s1.y);
        z[4] = di * (a1.x + s2.x); z[5] = di * (a1.y + s2.y);
        z[6] = di * (a1.z + s3.x); z[7] = di * (a1.w + s3.y);
        if constexpr (MODE >= 1) {
            #pragma unroll
            for (int q = 0; q < 8; ++q) {
                float zz = z[q] + b[f0 + q];
                if constexpr (MODE == 2)
                    zz = (zz - m[f0+q]) * rsqrtf(vv[f0+q] + EPS) * g[f0+q] + be[f0+q];
                z[q] = fmaxf(zz, 0.f);
            }
        }
        if constexpr (MODE == 4) {
            // fused 16->3 linear: p[c] = sum_q z[q] * Wf[(f0+q)*3+c]
            float p0 = 0.f, p1 = 0.f, p2 = 0.f;
            #pragma unroll
            for (int q = 0; q < 8; ++q) {
                float zq = z[q];
                p0 += zq * g[(f0 + q) * 3 + 0];
                p1 += zq * g[(f0 + q) * 3 + 1];
                p2 += zq * g[(f0 + q) * 3 + 2];
            }
            p0 += __shfl_xor(p0, 1);
            p1 += __shfl_xor(p1, 1);
            p2 += __shfl_xor(p2, 1);
            if (hl == 0) {
                reinterpret_cast<float4*>(out + (size_t)node * 4)[0] =
                    make_float4(di * p0, di * p1, di * p2, 0.f);
            }
        } else {
            float4* o = reinterpret_cast<float4*>(out + (size_t)node * OSTRIDE + f0);
            o[0] = make_float4(z[0], z[1], z[2], z[3]);
            o[1] = make_float4(z[4], z[5], z[6], z[7]);
        }
    }
}

extern "C" void kernel_launch(void* const* d_in, const int* in_sizes, int n_in,
                              void* d_out, int out_size, void* d_ws, size_t ws_size,
                              hipStream_t stream) {
    const float* x   = (const float*)d_in[0];
    const int*   src = (const int*)  d_in[1];
    const int*   dst = (const int*)  d_in[2];
    const float* W1  = (const float*)d_in[3];
    const float* b1  = (const float*)d_in[4];
    const float* g1  = (const float*)d_in[5];
    const float* be1 = (const float*)d_in[6];
    const float* m1  = (const float*)d_in[7];
    const float* v1  = (const float*)d_in[8];
    const float* W2  = (const float*)d_in[9];
    const float* b2  = (const float*)d_in[10];
    const float* g2  = (const float*)d_in[11];
    const float* be2 = (const float*)d_in[12];
    const float* m2  = (const float*)d_in[13];
    const float* v2  = (const float*)d_in[14];
    const float* W3  = (const float*)d_in[15];
    const float* b3  = (const float*)d_in[16];
    const float* W4  = (const float*)d_in[17];
    const float* b4  = (const float*)d_in[18];
    float* out = (float*)d_out;

    // workspace layout (4-byte units)
    char* wsb = (char*)d_ws;
    float*    dinv    = (float*)wsb;                    // 100352
    int*      cnt     = (int*)(wsb + 100352ull * 4);    // 100352
    int*      rowp    = (int*)(wsb + 200704ull * 4);    // 100352
    int*      gcur    = (int*)(wsb + 301056ull * 4);    // 512
    int*      binBase = (int*)(wsb + 301568ull * 4);    // 512
    int*      csr     = (int*)(wsb + 302080ull * 4);    // NE
    float*    HS      = (float*)(wsb + (302080ull + NE) * 4);              // NN*64 region
    __half*   HSh     = (__half*)HS;                                        // f16 view
    float*    X       = (float*)(wsb + (302080ull + NE + 6400000ull) * 4); // NN*64
    unsigned* ebuf    = (unsigned*)X;  // aliases X (NB*CAP2 = 3.6M <= 6.4M)
    float*    G       = (float*)(wsb + (302080ull + NE + 12800000ull) * 4); // NN*8
    float*    HS4     = (float*)(wsb + (302080ull + NE + 12800000ull + 800000ull) * 4); // NN*4

    const int BLK = 256;
    const int gW4 = ((NN + 3) / 4 * 64 + BLK - 1) / BLK;   // four nodes per wave

    // ---- CSR build (2-pass LDS counting sort) + rowp/cnt/dinv + f16 stage1 ----
    k_seed   <<<2, 256, 0, stream>>>(gcur);
    k_part1  <<<NBLK1, 512, 0, stream>>>(src, dst, gcur, ebuf);
    k_binscan<<<1, 512, 0, stream>>>(gcur, binBase);
    k_part2  <<<NB, 512, 0, stream>>>(ebuf, binBase, csr, rowp, cnt, dinv, x, HSh);

    // ---- Layer 1: f16 gather at F_in=5 (pad 8), then 5->64 GEMM+BN+ReLU ----
    k_gather_h<8, 0, 8><<<gW4, BLK, 0, stream>>>(rowp, cnt, csr, HSh, dinv,
        nullptr, nullptr, nullptr, nullptr, nullptr, G);
    k_lin<8, 5, 64, 64, 2><<<(NN + 3) / 4, BLK, 0, stream>>>(
        G, W1, nullptr, b1, g1, be1, m1, v1, X, nullptr);

    // ---- Layer 2: 64 -> 32 GEMM (f16 table), single 32-wide gather ----
    k_lin<64, 64, 32, 32, 1><<<(NN + 7) / 8, BLK, 0, stream>>>(
        X, W2, dinv, nullptr, nullptr, nullptr, nullptr, nullptr, nullptr, HSh);
    k_gather_h<32, 2, 32><<<gW4, BLK, 0, stream>>>(rowp, cnt, csr, HSh, dinv,
        b2, g2, be2, m2, v2, X);

    // ---- Layer 3: 32 -> 16 GEMM (f16 table), gather + fused 16->3 W4 ----
    k_lin<32, 32, 16, 16, 1><<<(NN + 15) / 16, BLK, 0, stream>>>(
        X, W3, dinv, nullptr, nullptr, nullptr, nullptr, nullptr, nullptr, HSh);
    k_gather_h<16, 4, 16><<<gW4, BLK, 0, stream>>>(rowp, cnt, csr, HSh, dinv,
        b3, W4, nullptr, nullptr, nullptr, HS4);

    // ---- Layer 4: gather at 4 (f32 table), logits ----
    k_gather<4, 3><<<gW4, BLK, 0, stream>>>(rowp, cnt, csr, HS4, dinv, b4, out);
}

// Round 20
// 209.554 us; speedup vs baseline: 1.1594x; 1.0489x over previous
//
#include <hip/hip_runtime.h>
#include <hip/hip_fp16.h>

static constexpr int NN = 100000;   // nodes
static constexpr int NE = 3200000;  // edges
static constexpr float EPS = 1e-5f;
static constexpr int NB   = 391;    // coarse bins (dst>>8), 256 nodes each
static constexpr int CAP2 = 9216;   // bin capacity (mean 8192 + ~11 sigma)
static constexpr int CH1  = 4096;   // pass-1 edges per block
static constexpr int NBLK1 = (NE + CH1 - 1) / CH1;   // 782

typedef _Float16 h2f __attribute__((ext_vector_type(2)));

__device__ __forceinline__ h2f u2h2(unsigned u) {
    union { unsigned u; h2f h; } cv; cv.u = u; return cv.h;
}

// ---- seed per-bin global cursors to padded bin bases ---------------------
__global__ void k_seed(int* __restrict__ gcur) {
    int t = blockIdx.x * blockDim.x + threadIdx.x;
    if (t < NB) gcur[t] = t * CAP2;
}

// ---- pass 1: LDS counting-sort chunk into coarse bins, coalesced out -----
__global__ __launch_bounds__(512) void k_part1(const int* __restrict__ src,
                                               const int* __restrict__ dst,
                                               int* __restrict__ gcur,
                                               unsigned* __restrict__ ebuf) {
    __shared__ unsigned stage[CH1];
    __shared__ unsigned short bins[CH1];
    __shared__ int hist[NB], lbase[NB + 1], lcur[NB], gbase[NB];
    int tid = threadIdx.x;
    int e0 = blockIdx.x * CH1;
    int n = min(CH1, NE - e0);

    for (int t = tid; t < NB; t += 512) { hist[t] = 0; lcur[t] = 0; }
    __syncthreads();
    for (int i = tid; i < n; i += 512) atomicAdd(&hist[dst[e0 + i] >> 8], 1);
    __syncthreads();
    for (int t = tid; t < NB; t += 512) gbase[t] = atomicAdd(&gcur[t], hist[t]);
    if (tid < 64) {                       // wave exclusive scan hist -> lbase
        int lane = tid, sum = 0, pre[7];
        #pragma unroll
        for (int k = 0; k < 7; ++k) {
            int idx = lane * 7 + k;
            int v = (idx < NB) ? hist[idx] : 0;
            pre[k] = sum; sum += v;
        }
        int inc = sum;
        #pragma unroll
        for (int off = 1; off < 64; off <<= 1) {
            int t = __shfl_up(inc, off);
            if (lane >= off) inc += t;
        }
        int excl = inc - sum;
        #pragma unroll
        for (int k = 0; k < 7; ++k) {
            int idx = lane * 7 + k;
            if (idx < NB + 1) lbase[idx] = excl + pre[k];
        }
    }
    __syncthreads();
    for (int i = tid; i < n; i += 512) {
        int d = dst[e0 + i];
        int b = d >> 8;
        int r = atomicAdd(&lcur[b], 1);
        int p = lbase[b] + r;
        stage[p] = ((unsigned)(d & 255) << 17) | (unsigned)src[e0 + i];
        bins[p] = (unsigned short)b;
    }
    __syncthreads();
    for (int i = tid; i < n; i += 512) {
        int b = bins[i];
        ebuf[gbase[b] + (i - lbase[b])] = stage[i];
    }
}

// ---- exact bin-base scan (392 values) ------------------------------------
__global__ void k_binscan(const int* __restrict__ gcur, int* __restrict__ binBase) {
    __shared__ int s[512];
    int t = threadIdx.x;
    int v = (t < NB) ? (gcur[t] - t * CAP2) : 0;
    s[t] = v;
    __syncthreads();
    for (int off = 1; off < 512; off <<= 1) {
        int x = (t >= off) ? s[t - off] : 0;
        __syncthreads();
        s[t] += x;
        __syncthreads();
    }
    if (t < NB + 1) binBase[t] = s[t] - v;   // exclusive (v=0 for t==NB)
}

// ---- pass 2: fine sort bin -> CSR + rowp/cnt/dinv + fused f16 stage1 ------
__global__ __launch_bounds__(512) void k_part2(const unsigned* __restrict__ ebuf,
                                               const int* __restrict__ binBase,
                                               int* __restrict__ csr, int* __restrict__ rowp,
                                               int* __restrict__ cnt, float* __restrict__ dinv,
                                               const float* __restrict__ x,
                                               __half* __restrict__ q) {
    __shared__ unsigned s2[CAP2];
    __shared__ int lhist[256], lrow[257];
    __shared__ float ldinv[256];
    int tid = threadIdx.x, b = blockIdx.x;
    int base = b * CAP2;
    int o0 = binBase[b], m = binBase[b + 1] - o0;

    if (tid < 256) lhist[tid] = 0;
    __syncthreads();
    for (int i = tid; i < m; i += 512) atomicAdd(&lhist[ebuf[base + i] >> 17], 1);
    __syncthreads();
    if (tid < 64) {                       // wave exclusive scan lhist -> lrow
        int lane = tid, sum = 0, pre[4];
        #pragma unroll
        for (int k = 0; k < 4; ++k) { pre[k] = sum; sum += lhist[lane * 4 + k]; }
        int inc = sum;
        #pragma unroll
        for (int off = 1; off < 64; off <<= 1) {
            int t = __shfl_up(inc, off);
            if (lane >= off) inc += t;
        }
        int excl = inc - sum;
        #pragma unroll
        for (int k = 0; k < 4; ++k) lrow[lane * 4 + k] = excl + pre[k];
        if (lane == 63) lrow[256] = excl + sum;
    }
    __syncthreads();
    if (tid < 256) lhist[tid] = 0;        // reuse as cursor
    __syncthreads();
    for (int i = tid; i < m; i += 512) {
        unsigned p = ebuf[base + i];
        int nd = (int)(p >> 17);
        int r = atomicAdd(&lhist[nd], 1);
        s2[lrow[nd] + r] = p & 0x1FFFFu;
    }
    __syncthreads();
    for (int i = tid; i < m; i += 512) csr[o0 + i] = (int)s2[i];
    int ng = (b << 8) + tid;
    if (tid < 256 && ng < NN) {
        int c = lrow[tid + 1] - lrow[tid];
        rowp[ng] = o0 + lrow[tid];
        cnt[ng] = c;
        float dv = rsqrtf((float)c + 1.f);
        dinv[ng] = dv;
        ldinv[tid] = dv;
    }
    __syncthreads();
    // fused layer-1 staging (f16): q[node, 0..7] = dinv*x[node, 0..4], pad 0
    int nmax = min(256, NN - (b << 8));
    for (int idx = tid; idx < nmax * 8; idx += 512) {
        int nl = idx >> 3, k = idx & 7;
        int node = (b << 8) + nl;
        q[(size_t)node * 8 + k] = __float2half((k < 5) ? x[node * 5 + k] * ldinv[nl] : 0.f);
    }
}

// ---- LDS-tiled dense linear ----------------------------------------------
// MODE 1: out f16 = a*dinv.                      (layer 2,3 pre-gather)
// MODE 2: out f32 = relu(bn(a + b)).             (layer-1 tail)
template<int INP, int IN, int OUT, int OUTP, int MODE>
__global__ __launch_bounds__(256) void k_lin(
        const float* __restrict__ in, const float* __restrict__ W,
        const float* __restrict__ dinv, const float* __restrict__ b,
        const float* __restrict__ g, const float* __restrict__ be,
        const float* __restrict__ m, const float* __restrict__ vv,
        float* __restrict__ outf, __half* __restrict__ outh) {
    constexpr int NPB = 256 / OUTP;   // nodes per block
    __shared__ float srow[NPB * INP];
    __shared__ float sW[IN * OUT];
    int tid = threadIdx.x;
    size_t node0 = (size_t)blockIdx.x * NPB;

    for (int t = tid; t < IN * OUT; t += 256) sW[t] = W[t];
    const float4* in4 = reinterpret_cast<const float4*>(in + node0 * INP);
    float4* s4 = reinterpret_cast<float4*>(srow);
    constexpr int TOT4 = NPB * INP / 4;
    #pragma unroll 1
    for (int t = tid; t < TOT4; t += 256) s4[t] = in4[t];
    __syncthreads();

    int il = tid / OUTP, f = tid - il * OUTP;
    size_t node = node0 + il;
    if (node >= NN) return;
    const float* row = srow + il * INP;
    float a = 0.f;
    if (f < OUT) {
        #pragma unroll
        for (int k = 0; k < IN; ++k) a += row[k] * sW[k * OUT + f];
    }
    if constexpr (MODE == 1) {
        outh[node * OUT + f] = __float2half(a * dinv[node]);
    } else {
        float z = a + b[f];
        z = (z - m[f]) * rsqrtf(vv[f] + EPS) * g[f] + be[f];
        outf[node * OUT + f] = fmaxf(z, 0.f);
    }
}

// ---- f32 gather: FOUR nodes per wave (16-lane groups), layer 4 ------------
// MODE 3: bias + write 3 floats (logits).  csr prefetched across chunks.
template<int F, int MODE>
__global__ __launch_bounds__(256) void k_gather(
        const int* __restrict__ row_ptr, const int* __restrict__ cnt,
        const int* __restrict__ csr, const float* __restrict__ hs,
        const float* __restrict__ dinv, const float* __restrict__ b,
        float* __restrict__ out) {
    constexpr int F4   = F / 4;       // lanes per edge (float4 each)
    constexpr int EPI  = 16 / F4;     // edges per iteration per group
    constexpr int ITER = F4;

    int wid  = (blockIdx.x * blockDim.x + threadIdx.x) >> 6;
    int lane = threadIdx.x & 63;
    int grp  = lane >> 4, hl = lane & 15;
    int node = wid * 4 + grp;
    if (node >= NN) return;
    int c = hl & (F4 - 1);
    int e = hl / F4;

    int start = row_ptr[node];
    int n     = cnt[node];

    float4 a = make_float4(0.f, 0.f, 0.f, 0.f);
    int my = (hl < n) ? csr[start + hl] : 0;          // prologue csr load
    for (int base = 0; base < n; base += 16) {
        int rem = n - base;
        int remn = rem - 16;                          // next-chunk prefetch
        int myn = (remn > 0 && hl < remn) ? csr[start + base + 16 + hl] : 0;
        #pragma unroll
        for (int k = 0; k < ITER; ++k) {
            if (k * EPI >= rem) break;        // per-group, exec-masked
            int j = e + k * EPI;
            int t = __shfl(my, grp * 16 + j);
            bool act = (j < rem);
            int s = act ? t : 0;
            float4 v = reinterpret_cast<const float4*>(hs + (size_t)s * F)[c];
            if (act) { a.x += v.x; a.y += v.y; a.z += v.z; a.w += v.w; }
        }
        my = myn;
    }
    #pragma unroll
    for (int mask = F4; mask < 16; mask <<= 1) {
        a.x += __shfl_xor(a.x, mask);
        a.y += __shfl_xor(a.y, mask);
        a.z += __shfl_xor(a.z, mask);
        a.w += __shfl_xor(a.w, mask);
    }

    if (hl < F4) {
        float4 self = reinterpret_cast<const float4*>(hs + (size_t)node * F)[hl];
        float di = dinv[node];
        float4 z;
        z.x = di * (a.x + self.x);
        z.y = di * (a.y + self.y);
        z.z = di * (a.z + self.z);
        z.w = di * (a.w + self.w);
        if constexpr (MODE == 3) {
            float* o = out + (size_t)node * 3;
            o[0] = z.x + b[0]; o[1] = z.y + b[1]; o[2] = z.z + b[2];
        } else {
            reinterpret_cast<float4*>(out + (size_t)node * F)[hl] = z;
        }
    }
}

// ---- f16 gather: FOUR nodes per wave, 16B/lane (8 halves), fdot2 ----------
// MODE 0: scale only.  MODE 1: bias+relu.  MODE 2: bias+bn+relu.
// MODE 4: bias+relu then fused 16->3 linear (Wf via g) -> padded-4 f32 out.
// csr prefetched across chunks.
template<int F, int MODE, int OSTRIDE>
__global__ __launch_bounds__(256) void k_gather_h(
        const int* __restrict__ row_ptr, const int* __restrict__ cnt,
        const int* __restrict__ csr, const __half* __restrict__ hs,
        const float* __restrict__ dinv, const float* __restrict__ b,
        const float* __restrict__ g, const float* __restrict__ be,
        const float* __restrict__ m, const float* __restrict__ vv,
        float* __restrict__ out) {
    constexpr int F4   = F / 8;       // lanes per edge (8 halves = 16B each)
    constexpr int EPI  = 16 / F4;     // edges per iteration per group
    constexpr int ITER = F4;          // EPI*ITER = 16

    int wid  = (blockIdx.x * blockDim.x + threadIdx.x) >> 6;
    int lane = threadIdx.x & 63;
    int grp  = lane >> 4, hl = lane & 15;
    int node = wid * 4 + grp;
    if (node >= NN) return;
    int c = hl & (F4 - 1);
    int e = hl / F4;

    int start = row_ptr[node];
    int n     = cnt[node];

    const h2f SEL_A = {(_Float16)1.f, (_Float16)0.f};
    const h2f SEL_B = {(_Float16)0.f, (_Float16)1.f};
    const h2f SEL_Z = {(_Float16)0.f, (_Float16)0.f};

    float4 a0 = make_float4(0.f, 0.f, 0.f, 0.f);
    float4 a1 = make_float4(0.f, 0.f, 0.f, 0.f);
    int my = (hl < n) ? csr[start + hl] : 0;          // prologue csr load
    for (int base = 0; base < n; base += 16) {
        int rem = n - base;
        int remn = rem - 16;                          // next-chunk prefetch
        int myn = (remn > 0 && hl < remn) ? csr[start + base + 16 + hl] : 0;
        #pragma unroll
        for (int k = 0; k < ITER; ++k) {
            if (k * EPI >= rem) break;        // per-group, exec-masked
            int j = e + k * EPI;
            int t = __shfl(my, grp * 16 + j);
            bool act = (j < rem);
            int s = act ? t : 0;
            uint4 r = reinterpret_cast<const uint4*>(hs + (size_t)s * F)[c];
            h2f sA = act ? SEL_A : SEL_Z;
            h2f sB = act ? SEL_B : SEL_Z;
            h2f h0 = u2h2(r.x), h1 = u2h2(r.y), h2 = u2h2(r.z), h3 = u2h2(r.w);
            a0.x = __builtin_amdgcn_fdot2(h0, sA, a0.x, false);
            a0.y = __builtin_amdgcn_fdot2(h0, sB, a0.y, false);
            a0.z = __builtin_amdgcn_fdot2(h1, sA, a0.z, false);
            a0.w = __builtin_amdgcn_fdot2(h1, sB, a0.w, false);
            a1.x = __builtin_amdgcn_fdot2(h2, sA, a1.x, false);
            a1.y = __builtin_amdgcn_fdot2(h2, sB, a1.y, false);
            a1.z = __builtin_amdgcn_fdot2(h3, sA, a1.z, false);
            a1.w = __builtin_amdgcn_fdot2(h3, sB, a1.w, false);
        }
        my = myn;
    }
    #pragma unroll
    for (int mask = F4; mask < 16; mask <<= 1) {
        a0.x += __shfl_xor(a0.x, mask);
        a0.y += __shfl_xor(a0.y, mask);
        a0.z += __shfl_xor(a0.z, mask);
        a0.w += __shfl_xor(a0.w, mask);
        a1.x += __shfl_xor(a1.x, mask);
        a1.y += __shfl_xor(a1.y, mask);
        a1.z += __shfl_xor(a1.z, mask);
        a1.w += __shfl_xor(a1.w, mask);
    }

    if (hl < F4) {
        uint4 r = reinterpret_cast<const uint4*>(hs + (size_t)node * F)[hl];
        float2 s0 = __half22float2(*reinterpret_cast<__half2*>(&r.x));
        float2 s1 = __half22float2(*reinterpret_cast<__half2*>(&r.y));
        float2 s2 = __half22float2(*reinterpret_cast<__half2*>(&r.z));
        float2 s3 = __half22float2(*reinterpret_cast<__half2*>(&r.w));
        float di = dinv[node];
        int f0 = hl * 8;
        float z[8];
        z[0] = di * (a0.x + s0.x); z[1] = di * (a0.y + s0.y);
        z[2] = di * (a0.z + s1.x); z[3] = di * (a0.w + s1.y);
        z[4] = di * (a1.x + s2.x); z[5] = di * (a1.y + s2.y);
        z[6] = di * (a1.z + s3.x); z[7] = di * (a1.w + s3.y);
        if constexpr (MODE >= 1) {
            #pragma unroll
            for (int q = 0; q < 8; ++q) {
                float zz = z[q] + b[f0 + q];
                if constexpr (MODE == 2)
                    zz = (zz - m[f0+q]) * rsqrtf(vv[f0+q] + EPS) * g[f0+q] + be[f0+q];
                z[q] = fmaxf(zz, 0.f);
            }
        }
        if constexpr (MODE == 4) {
            // fused 16->3 linear: p[c] = sum_q z[q] * Wf[(f0+q)*3+c]
            float p0 = 0.f, p1 = 0.f, p2 = 0.f;
            #pragma unroll
            for (int q = 0; q < 8; ++q) {
                float zq = z[q];
                p0 += zq * g[(f0 + q) * 3 + 0];
                p1 += zq * g[(f0 + q) * 3 + 1];
                p2 += zq * g[(f0 + q) * 3 + 2];
            }
            p0 += __shfl_xor(p0, 1);
            p1 += __shfl_xor(p1, 1);
            p2 += __shfl_xor(p2, 1);
            if (hl == 0) {
                reinterpret_cast<float4*>(out + (size_t)node * 4)[0] =
                    make_float4(di * p0, di * p1, di * p2, 0.f);
            }
        } else {
            float4* o = reinterpret_cast<float4*>(out + (size_t)node * OSTRIDE + f0);
            o[0] = make_float4(z[0], z[1], z[2], z[3]);
            o[1] = make_float4(z[4], z[5], z[6], z[7]);
        }
    }
}

extern "C" void kernel_launch(void* const* d_in, const int* in_sizes, int n_in,
                              void* d_out, int out_size, void* d_ws, size_t ws_size,
                              hipStream_t stream) {
    const float* x   = (const float*)d_in[0];
    const int*   src = (const int*)  d_in[1];
    const int*   dst = (const int*)  d_in[2];
    const float* W1  = (const float*)d_in[3];
    const float* b1  = (const float*)d_in[4];
    const float* g1  = (const float*)d_in[5];
    const float* be1 = (const float*)d_in[6];
    const float* m1  = (const float*)d_in[7];
    const float* v1  = (const float*)d_in[8];
    const float* W2  = (const float*)d_in[9];
    const float* b2  = (const float*)d_in[10];
    const float* g2  = (const float*)d_in[11];
    const float* be2 = (const float*)d_in[12];
    const float* m2  = (const float*)d_in[13];
    const float* v2  = (const float*)d_in[14];
    const float* W3  = (const float*)d_in[15];
    const float* b3  = (const float*)d_in[16];
    const float* W4  = (const float*)d_in[17];
    const float* b4  = (const float*)d_in[18];
    float* out = (float*)d_out;

    // workspace layout (4-byte units)
    char* wsb = (char*)d_ws;
    float*    dinv    = (float*)wsb;                    // 100352
    int*      cnt     = (int*)(wsb + 100352ull * 4);    // 100352
    int*      rowp    = (int*)(wsb + 200704ull * 4);    // 100352
    int*      gcur    = (int*)(wsb + 301056ull * 4);    // 512
    int*      binBase = (int*)(wsb + 301568ull * 4);    // 512
    int*      csr     = (int*)(wsb + 302080ull * 4);    // NE
    float*    HS      = (float*)(wsb + (302080ull + NE) * 4);              // NN*64 region
    __half*   HSh     = (__half*)HS;                                        // f16 view
    float*    X       = (float*)(wsb + (302080ull + NE + 6400000ull) * 4); // NN*64
    unsigned* ebuf    = (unsigned*)X;  // aliases X (NB*CAP2 = 3.6M <= 6.4M)
    float*    G       = (float*)(wsb + (302080ull + NE + 12800000ull) * 4); // NN*8
    float*    HS4     = (float*)(wsb + (302080ull + NE + 12800000ull + 800000ull) * 4); // NN*4

    const int BLK = 256;
    const int gW4 = ((NN + 3) / 4 * 64 + BLK - 1) / BLK;   // four nodes per wave

    // ---- CSR build (2-pass LDS counting sort) + rowp/cnt/dinv + f16 stage1 ----
    k_seed   <<<2, 256, 0, stream>>>(gcur);
    k_part1  <<<NBLK1, 512, 0, stream>>>(src, dst, gcur, ebuf);
    k_binscan<<<1, 512, 0, stream>>>(gcur, binBase);
    k_part2  <<<NB, 512, 0, stream>>>(ebuf, binBase, csr, rowp, cnt, dinv, x, HSh);

    // ---- Layer 1: f16 gather at F_in=5 (pad 8), then 5->64 GEMM+BN+ReLU ----
    k_gather_h<8, 0, 8><<<gW4, BLK, 0, stream>>>(rowp, cnt, csr, HSh, dinv,
        nullptr, nullptr, nullptr, nullptr, nullptr, G);
    k_lin<8, 5, 64, 64, 2><<<(NN + 3) / 4, BLK, 0, stream>>>(
        G, W1, nullptr, b1, g1, be1, m1, v1, X, nullptr);

    // ---- Layer 2: 64 -> 32 GEMM (f16 table), single 32-wide gather ----
    k_lin<64, 64, 32, 32, 1><<<(NN + 7) / 8, BLK, 0, stream>>>(
        X, W2, dinv, nullptr, nullptr, nullptr, nullptr, nullptr, nullptr, HSh);
    k_gather_h<32, 2, 32><<<gW4, BLK, 0, stream>>>(rowp, cnt, csr, HSh, dinv,
        b2, g2, be2, m2, v2, X);

    // ---- Layer 3: 32 -> 16 GEMM (f16 table), gather + fused 16->3 W4 ----
    k_lin<32, 32, 16, 16, 1><<<(NN + 15) / 16, BLK, 0, stream>>>(
        X, W3, dinv, nullptr, nullptr, nullptr, nullptr, nullptr, nullptr, HSh);
    k_gather_h<16, 4, 16><<<gW4, BLK, 0, stream>>>(rowp, cnt, csr, HSh, dinv,
        b3, W4, nullptr, nullptr, nullptr, HS4);

    // ---- Layer 4: gather at 4 (f32 table), logits ----
    k_gather<4, 3><<<gW4, BLK, 0, stream>>>(rowp, cnt, csr, HS4, dinv, b4, out);
}